// Round 1
// baseline (1952.454 us; speedup 1.0000x reference)
//
#include <hip/hip_runtime.h>

namespace {
constexpr int kB   = 8;
constexpr int kN   = 5000;
constexpr int kE   = 40000;
constexpr int kF   = 64;
constexpr int kFE  = 16;
constexpr int kFil = 96;
constexpr int kDm  = 144;  // 2F + FE
constexpr int kDu  = 160;  // F + FILTERS
constexpr float kEps = 1e-3f;
}

// ---------------------------------------------------------------------------
// Kernel 1: per-edge message = LN(relu([n_src, n_dst, e_feat] @ Wm + bm))
// Also atomically accumulates messages into agg[b, dst, :].
// One thread per edge; Wm staged in LDS (wave-uniform broadcast reads).
// ---------------------------------------------------------------------------
__global__ __launch_bounds__(256, 2) void gnn_msg_kernel(
    const float* __restrict__ nodes,   // (B,N,F)
    const float* __restrict__ efeat,   // (B,E,FE)
    const int*   __restrict__ edges,   // (B,E,2)
    const float* __restrict__ Wm,      // (144,96)
    const float* __restrict__ bm,      // (96)
    const float* __restrict__ gamma_,  // (96)
    const float* __restrict__ beta_,   // (96)
    float* __restrict__ out_msg,       // (B,E,96)
    float* __restrict__ agg)           // (B,N,96)  pre-zeroed
{
    __shared__ float sW[kDm * kFil];          // 55296 B
    __shared__ float sb[kFil], sg[kFil], sbe[kFil];

    for (int i = threadIdx.x; i < kDm * kFil; i += 256) sW[i] = Wm[i];
    if (threadIdx.x < kFil) {
        sb[threadIdx.x]  = bm[threadIdx.x];
        sg[threadIdx.x]  = gamma_[threadIdx.x];
        sbe[threadIdx.x] = beta_[threadIdx.x];
    }
    __syncthreads();

    const int idx = blockIdx.x * 256 + threadIdx.x;   // flat b*E + e
    if (idx >= kB * kE) return;
    const int b = idx / kE;

    const int src = edges[(size_t)idx * 2 + 0];
    const int dst = edges[(size_t)idx * 2 + 1];

    const float* srow = nodes + ((size_t)b * kN + src) * kF;
    const float* drow = nodes + ((size_t)b * kN + dst) * kF;
    const float* erow = efeat + (size_t)idx * kFE;

    float acc[kFil];
#pragma unroll
    for (int f = 0; f < kFil; ++f) acc[f] = sb[f];

    // 9 chunks of 16 inputs: 0..3 -> src row, 4..7 -> dst row, 8 -> edge feats
#pragma unroll 1
    for (int kc = 0; kc < 9; ++kc) {
        const float* bptr;
        if (kc < 4)      bptr = srow + kc * 16;
        else if (kc < 8) bptr = drow + (kc - 4) * 16;
        else             bptr = erow;
        const float4* p4 = reinterpret_cast<const float4*>(bptr);
        float4 x0 = p4[0], x1 = p4[1], x2 = p4[2], x3 = p4[3];
        float xin[16] = {x0.x, x0.y, x0.z, x0.w, x1.x, x1.y, x1.z, x1.w,
                         x2.x, x2.y, x2.z, x2.w, x3.x, x3.y, x3.z, x3.w};
        const float* wbase = &sW[(size_t)kc * 16 * kFil];
#pragma unroll
        for (int kk = 0; kk < 16; ++kk) {
            const float x = xin[kk];
            const float* wrow = wbase + kk * kFil;
#pragma unroll
            for (int f = 0; f < kFil; ++f)
                acc[f] = fmaf(x, wrow[f], acc[f]);
        }
    }

    // ReLU + LayerNorm (all 96 values live in this thread's registers)
    float s = 0.f;
#pragma unroll
    for (int f = 0; f < kFil; ++f) {
        acc[f] = fmaxf(acc[f], 0.f);
        s += acc[f];
    }
    const float mu = s * (1.0f / kFil);
    float v = 0.f;
#pragma unroll
    for (int f = 0; f < kFil; ++f) {
        const float d = acc[f] - mu;
        v = fmaf(d, d, v);
    }
    const float inv = rsqrtf(v * (1.0f / kFil) + kEps);
#pragma unroll
    for (int f = 0; f < kFil; ++f)
        acc[f] = (acc[f] - mu) * inv * sg[f] + sbe[f];

    // write messages (float4 stores, 384 B per thread)
    float* mrow = out_msg + (size_t)idx * kFil;
#pragma unroll
    for (int f = 0; f < kFil; f += 4) {
        float4 o = {acc[f], acc[f + 1], acc[f + 2], acc[f + 3]};
        *reinterpret_cast<float4*>(mrow + f) = o;
    }

    // aggregate into destination node
    float* arow = agg + ((size_t)b * kN + dst) * kFil;
#pragma unroll
    for (int f = 0; f < kFil; ++f)
        atomicAdd(arow + f, acc[f]);
}

// ---------------------------------------------------------------------------
// Kernel 2: per-node update = LN(relu([node, agg] @ Wu + bu))
// ---------------------------------------------------------------------------
__global__ __launch_bounds__(256, 2) void gnn_upd_kernel(
    const float* __restrict__ nodes,   // (B,N,F)
    const float* __restrict__ agg,     // (B,N,96)
    const float* __restrict__ Wu,      // (160,96)
    const float* __restrict__ bu,      // (96)
    const float* __restrict__ gamma_,  // (96)
    const float* __restrict__ beta_,   // (96)
    float* __restrict__ out_upd)       // (B,N,96)
{
    __shared__ float sW[kDu * kFil];          // 61440 B
    __shared__ float sb[kFil], sg[kFil], sbe[kFil];

    for (int i = threadIdx.x; i < kDu * kFil; i += 256) sW[i] = Wu[i];
    if (threadIdx.x < kFil) {
        sb[threadIdx.x]  = bu[threadIdx.x];
        sg[threadIdx.x]  = gamma_[threadIdx.x];
        sbe[threadIdx.x] = beta_[threadIdx.x];
    }
    __syncthreads();

    const int idx = blockIdx.x * 256 + threadIdx.x;   // flat b*N + n
    if (idx >= kB * kN) return;

    const float* srow = nodes + (size_t)idx * kF;
    const float* arow = agg + (size_t)idx * kFil;

    float acc[kFil];
#pragma unroll
    for (int f = 0; f < kFil; ++f) acc[f] = sb[f];

    // 10 chunks of 16 inputs: 0..3 -> node row, 4..9 -> agg row
#pragma unroll 1
    for (int kc = 0; kc < 10; ++kc) {
        const float* bptr;
        if (kc < 4) bptr = srow + kc * 16;
        else        bptr = arow + (kc - 4) * 16;
        const float4* p4 = reinterpret_cast<const float4*>(bptr);
        float4 x0 = p4[0], x1 = p4[1], x2 = p4[2], x3 = p4[3];
        float xin[16] = {x0.x, x0.y, x0.z, x0.w, x1.x, x1.y, x1.z, x1.w,
                         x2.x, x2.y, x2.z, x2.w, x3.x, x3.y, x3.z, x3.w};
        const float* wbase = &sW[(size_t)kc * 16 * kFil];
#pragma unroll
        for (int kk = 0; kk < 16; ++kk) {
            const float x = xin[kk];
            const float* wrow = wbase + kk * kFil;
#pragma unroll
            for (int f = 0; f < kFil; ++f)
                acc[f] = fmaf(x, wrow[f], acc[f]);
        }
    }

    float s = 0.f;
#pragma unroll
    for (int f = 0; f < kFil; ++f) {
        acc[f] = fmaxf(acc[f], 0.f);
        s += acc[f];
    }
    const float mu = s * (1.0f / kFil);
    float v = 0.f;
#pragma unroll
    for (int f = 0; f < kFil; ++f) {
        const float d = acc[f] - mu;
        v = fmaf(d, d, v);
    }
    const float inv = rsqrtf(v * (1.0f / kFil) + kEps);
#pragma unroll
    for (int f = 0; f < kFil; ++f)
        acc[f] = (acc[f] - mu) * inv * sg[f] + sbe[f];

    float* orow = out_upd + (size_t)idx * kFil;
#pragma unroll
    for (int f = 0; f < kFil; f += 4) {
        float4 o = {acc[f], acc[f + 1], acc[f + 2], acc[f + 3]};
        *reinterpret_cast<float4*>(orow + f) = o;
    }
}

extern "C" void kernel_launch(void* const* d_in, const int* in_sizes, int n_in,
                              void* d_out, int out_size, void* d_ws, size_t ws_size,
                              hipStream_t stream) {
    const float* nodes  = (const float*)d_in[0];
    const float* efeat  = (const float*)d_in[1];
    const int*   edges  = (const int*)d_in[2];
    const float* Wm     = (const float*)d_in[3];
    const float* bm     = (const float*)d_in[4];
    const float* ln_m_g = (const float*)d_in[5];
    const float* ln_m_b = (const float*)d_in[6];
    const float* Wu     = (const float*)d_in[7];
    const float* bu     = (const float*)d_in[8];
    const float* ln_u_g = (const float*)d_in[9];
    const float* ln_u_b = (const float*)d_in[10];

    float* out_upd = (float*)d_out;                           // (B,N,96) first
    float* out_msg = (float*)d_out + (size_t)kB * kN * kFil;  // (B,E,96) second
    float* agg     = (float*)d_ws;                            // (B,N,96) scratch

    const size_t agg_bytes = (size_t)kB * kN * kFil * sizeof(float);
    hipMemsetAsync(agg, 0, agg_bytes, stream);

    const int n_edge_thr = kB * kE;                 // 320000
    const int n_node_thr = kB * kN;                 // 40000
    gnn_msg_kernel<<<(n_edge_thr + 255) / 256, 256, 0, stream>>>(
        nodes, efeat, edges, Wm, bm, ln_m_g, ln_m_b, out_msg, agg);
    gnn_upd_kernel<<<(n_node_thr + 255) / 256, 256, 0, stream>>>(
        nodes, agg, Wu, bu, ln_u_g, ln_u_b, out_upd);
}

// Round 2
// 610.884 us; speedup vs baseline: 3.1961x; 3.1961x over previous
//
#include <hip/hip_runtime.h>

namespace {
constexpr int kB   = 8;
constexpr int kN   = 5000;
constexpr int kE   = 40000;
constexpr int kF   = 64;
constexpr int kFE  = 16;
constexpr int kFil = 96;
constexpr int kDm  = 144;  // 2F + FE
constexpr int kDu  = 160;  // F + FILTERS
constexpr float kEps = 1e-3f;
constexpr int kBN = kB * kN;   // 40000
constexpr int kBE = kB * kE;   // 320000
}

// ---------------------------------------------------------------------------
// CSR build: count -> scan -> scatter  (replaces 30.7M fp32 atomics with
// 2x 320k int atomics; fp32 atomic storm was the round-1 bottleneck)
// ---------------------------------------------------------------------------
__global__ void count_kernel(const int* __restrict__ edges, int* __restrict__ counts) {
    const int idx = blockIdx.x * 256 + threadIdx.x;
    if (idx >= kBE) return;
    const int b = idx / kE;
    const int dst = edges[(size_t)idx * 2 + 1];
    atomicAdd(&counts[b * kN + dst], 1);
}

__global__ __launch_bounds__(1024) void scan_kernel(const int* __restrict__ counts,
                                                    int* __restrict__ offsets) {
    __shared__ int part[1024];
    const int t = threadIdx.x;
    const int chunk = (kBN + 1023) / 1024;   // 40
    const int base = t * chunk;
    int s = 0;
    for (int i = 0; i < chunk; ++i) {
        const int j = base + i;
        if (j < kBN) s += counts[j];
    }
    part[t] = s;
    __syncthreads();
    for (int d = 1; d < 1024; d <<= 1) {
        const int v = (t >= d) ? part[t - d] : 0;
        __syncthreads();
        part[t] += v;
        __syncthreads();
    }
    int run = part[t] - s;   // exclusive prefix
    for (int i = 0; i < chunk; ++i) {
        const int j = base + i;
        if (j < kBN) {
            offsets[j] = run;
            run += counts[j];
        }
    }
}

__global__ void scatter_kernel(const int* __restrict__ edges,
                               const int* __restrict__ offsets,
                               int* __restrict__ cursor,
                               int* __restrict__ edge_ids) {
    const int idx = blockIdx.x * 256 + threadIdx.x;
    if (idx >= kBE) return;
    const int b = idx / kE;
    const int dst = edges[(size_t)idx * 2 + 1];
    const int node = b * kN + dst;
    const int pos = offsets[node] + atomicAdd(&cursor[node], 1);
    edge_ids[pos] = idx;
}

// ---------------------------------------------------------------------------
// Kernel: per-edge message = LN(relu([n_src, n_dst, e_feat] @ Wm + bm))
// No atomics. block=512 -> 2 blocks/CU (LDS 56.8KB), 16 waves/CU.
// ---------------------------------------------------------------------------
__global__ __launch_bounds__(512, 4) void gnn_msg_kernel(
    const float* __restrict__ nodes,   // (B,N,F)
    const float* __restrict__ efeat,   // (B,E,FE)
    const int*   __restrict__ edges,   // (B,E,2)
    const float* __restrict__ Wm,      // (144,96)
    const float* __restrict__ bm,      // (96)
    const float* __restrict__ gamma_,  // (96)
    const float* __restrict__ beta_,   // (96)
    float* __restrict__ out_msg)       // (B,E,96)
{
    __shared__ float sW[kDm * kFil];          // 55296 B
    __shared__ float sb[kFil], sg[kFil], sbe[kFil];

    for (int i = threadIdx.x; i < kDm * kFil; i += 512) sW[i] = Wm[i];
    if (threadIdx.x < kFil) {
        sb[threadIdx.x]  = bm[threadIdx.x];
        sg[threadIdx.x]  = gamma_[threadIdx.x];
        sbe[threadIdx.x] = beta_[threadIdx.x];
    }
    __syncthreads();

    const int idx = blockIdx.x * 512 + threadIdx.x;   // flat b*E + e  (320000 = 625*512 exact)
    const int b = idx / kE;

    const int src = edges[(size_t)idx * 2 + 0];
    const int dst = edges[(size_t)idx * 2 + 1];

    const float* srow = nodes + ((size_t)b * kN + src) * kF;
    const float* drow = nodes + ((size_t)b * kN + dst) * kF;
    const float* erow = efeat + (size_t)idx * kFE;

    float acc[kFil];
#pragma unroll
    for (int f = 0; f < kFil; ++f) acc[f] = sb[f];

    // 9 chunks of 16 inputs: 0..3 -> src row, 4..7 -> dst row, 8 -> edge feats
#pragma unroll 1
    for (int kc = 0; kc < 9; ++kc) {
        const float* bptr;
        if (kc < 4)      bptr = srow + kc * 16;
        else if (kc < 8) bptr = drow + (kc - 4) * 16;
        else             bptr = erow;
        const float4* p4 = reinterpret_cast<const float4*>(bptr);
        float4 x0 = p4[0], x1 = p4[1], x2 = p4[2], x3 = p4[3];
        float xin[16] = {x0.x, x0.y, x0.z, x0.w, x1.x, x1.y, x1.z, x1.w,
                         x2.x, x2.y, x2.z, x2.w, x3.x, x3.y, x3.z, x3.w};
        const float* wbase = &sW[(size_t)kc * 16 * kFil];
#pragma unroll
        for (int kk = 0; kk < 16; ++kk) {
            const float x = xin[kk];
            const float* wrow = wbase + kk * kFil;
#pragma unroll
            for (int f = 0; f < kFil; ++f)
                acc[f] = fmaf(x, wrow[f], acc[f]);
        }
    }

    // ReLU + LayerNorm (all 96 values live in this thread's registers)
    float s = 0.f;
#pragma unroll
    for (int f = 0; f < kFil; ++f) {
        acc[f] = fmaxf(acc[f], 0.f);
        s += acc[f];
    }
    const float mu = s * (1.0f / kFil);
    float v = 0.f;
#pragma unroll
    for (int f = 0; f < kFil; ++f) {
        const float d = acc[f] - mu;
        v = fmaf(d, d, v);
    }
    const float inv = rsqrtf(v * (1.0f / kFil) + kEps);
#pragma unroll
    for (int f = 0; f < kFil; ++f)
        acc[f] = (acc[f] - mu) * inv * sg[f] + sbe[f];

    float* mrow = out_msg + (size_t)idx * kFil;
#pragma unroll
    for (int f = 0; f < kFil; f += 4) {
        float4 o = {acc[f], acc[f + 1], acc[f + 2], acc[f + 3]};
        *reinterpret_cast<float4*>(mrow + f) = o;
    }
}

// ---------------------------------------------------------------------------
// Aggregate: 32 lanes per node; lanes 0..23 each own one float4 column chunk.
// Each message row is read as one coalesced 384B burst by lanes 0..23.
// ---------------------------------------------------------------------------
__global__ __launch_bounds__(256) void agg_kernel(
    const float* __restrict__ msg,        // (B,E,96)
    const int*   __restrict__ offsets,    // (B*N)
    const int*   __restrict__ counts,     // (B*N)
    const int*   __restrict__ edge_ids,   // (B*E)
    float* __restrict__ agg)              // (B,N,96)
{
    const int group = threadIdx.x >> 5;
    const int lane  = threadIdx.x & 31;
    const int node  = blockIdx.x * 8 + group;
    if (node >= kBN) return;
    const int start = offsets[node];
    const int cnt   = counts[node];
    if (lane < 24) {
        float4 acc = {0.f, 0.f, 0.f, 0.f};
        for (int e = 0; e < cnt; ++e) {
            const int eid = edge_ids[start + e];
            const float4 x =
                reinterpret_cast<const float4*>(msg + (size_t)eid * kFil)[lane];
            acc.x += x.x; acc.y += x.y; acc.z += x.z; acc.w += x.w;
        }
        reinterpret_cast<float4*>(agg + (size_t)node * kFil)[lane] = acc;
    }
}

// ---------------------------------------------------------------------------
// Update: per-node LN(relu([node, agg] @ Wu + bu))
// ---------------------------------------------------------------------------
__global__ __launch_bounds__(512, 4) void gnn_upd_kernel(
    const float* __restrict__ nodes,   // (B,N,F)
    const float* __restrict__ agg,     // (B,N,96)
    const float* __restrict__ Wu,      // (160,96)
    const float* __restrict__ bu,      // (96)
    const float* __restrict__ gamma_,  // (96)
    const float* __restrict__ beta_,   // (96)
    float* __restrict__ out_upd)       // (B,N,96)
{
    __shared__ float sW[kDu * kFil];          // 61440 B
    __shared__ float sb[kFil], sg[kFil], sbe[kFil];

    for (int i = threadIdx.x; i < kDu * kFil; i += 512) sW[i] = Wu[i];
    if (threadIdx.x < kFil) {
        sb[threadIdx.x]  = bu[threadIdx.x];
        sg[threadIdx.x]  = gamma_[threadIdx.x];
        sbe[threadIdx.x] = beta_[threadIdx.x];
    }
    __syncthreads();

    const int idx = blockIdx.x * 512 + threadIdx.x;   // flat b*N + n
    if (idx >= kBN) return;

    const float* srow = nodes + (size_t)idx * kF;
    const float* arow = agg + (size_t)idx * kFil;

    float acc[kFil];
#pragma unroll
    for (int f = 0; f < kFil; ++f) acc[f] = sb[f];

#pragma unroll 1
    for (int kc = 0; kc < 10; ++kc) {
        const float* bptr;
        if (kc < 4) bptr = srow + kc * 16;
        else        bptr = arow + (kc - 4) * 16;
        const float4* p4 = reinterpret_cast<const float4*>(bptr);
        float4 x0 = p4[0], x1 = p4[1], x2 = p4[2], x3 = p4[3];
        float xin[16] = {x0.x, x0.y, x0.z, x0.w, x1.x, x1.y, x1.z, x1.w,
                         x2.x, x2.y, x2.z, x2.w, x3.x, x3.y, x3.z, x3.w};
        const float* wbase = &sW[(size_t)kc * 16 * kFil];
#pragma unroll
        for (int kk = 0; kk < 16; ++kk) {
            const float x = xin[kk];
            const float* wrow = wbase + kk * kFil;
#pragma unroll
            for (int f = 0; f < kFil; ++f)
                acc[f] = fmaf(x, wrow[f], acc[f]);
        }
    }

    float s = 0.f;
#pragma unroll
    for (int f = 0; f < kFil; ++f) {
        acc[f] = fmaxf(acc[f], 0.f);
        s += acc[f];
    }
    const float mu = s * (1.0f / kFil);
    float v = 0.f;
#pragma unroll
    for (int f = 0; f < kFil; ++f) {
        const float d = acc[f] - mu;
        v = fmaf(d, d, v);
    }
    const float inv = rsqrtf(v * (1.0f / kFil) + kEps);
#pragma unroll
    for (int f = 0; f < kFil; ++f)
        acc[f] = (acc[f] - mu) * inv * sg[f] + sbe[f];

    float* orow = out_upd + (size_t)idx * kFil;
#pragma unroll
    for (int f = 0; f < kFil; f += 4) {
        float4 o = {acc[f], acc[f + 1], acc[f + 2], acc[f + 3]};
        *reinterpret_cast<float4*>(orow + f) = o;
    }
}

extern "C" void kernel_launch(void* const* d_in, const int* in_sizes, int n_in,
                              void* d_out, int out_size, void* d_ws, size_t ws_size,
                              hipStream_t stream) {
    const float* nodes  = (const float*)d_in[0];
    const float* efeat  = (const float*)d_in[1];
    const int*   edges  = (const int*)d_in[2];
    const float* Wm     = (const float*)d_in[3];
    const float* bm     = (const float*)d_in[4];
    const float* ln_m_g = (const float*)d_in[5];
    const float* ln_m_b = (const float*)d_in[6];
    const float* Wu     = (const float*)d_in[7];
    const float* bu     = (const float*)d_in[8];
    const float* ln_u_g = (const float*)d_in[9];
    const float* ln_u_b = (const float*)d_in[10];

    float* out_upd = (float*)d_out;                           // (B,N,96) first
    float* out_msg = (float*)d_out + (size_t)kBN * kFil;      // (B,E,96) second

    // workspace layout (~17.1 MB)
    float* agg      = (float*)d_ws;                           // B*N*96 floats
    int*   counts   = (int*)(agg + (size_t)kBN * kFil);       // 40000
    int*   cursor   = counts + kBN;                           // 40000
    int*   offsets  = cursor + kBN;                           // 40000
    int*   edge_ids = offsets + kBN;                          // 320000

    // zero counts + cursor (adjacent) in one memset
    hipMemsetAsync(counts, 0, (size_t)2 * kBN * sizeof(int), stream);

    count_kernel<<<(kBE + 255) / 256, 256, 0, stream>>>(edges, counts);
    scan_kernel<<<1, 1024, 0, stream>>>(counts, offsets);
    scatter_kernel<<<(kBE + 255) / 256, 256, 0, stream>>>(edges, offsets, cursor, edge_ids);

    gnn_msg_kernel<<<kBE / 512, 512, 0, stream>>>(
        nodes, efeat, edges, Wm, bm, ln_m_g, ln_m_b, out_msg);
    agg_kernel<<<(kBN + 7) / 8, 256, 0, stream>>>(
        out_msg, offsets, counts, edge_ids, agg);
    gnn_upd_kernel<<<(kBN + 511) / 512, 512, 0, stream>>>(
        nodes, agg, Wu, bu, ln_u_g, ln_u_b, out_upd);
}

// Round 3
// 516.275 us; speedup vs baseline: 3.7818x; 1.1833x over previous
//
#include <hip/hip_runtime.h>

namespace {
constexpr int kB   = 8;
constexpr int kN   = 5000;
constexpr int kE   = 40000;
constexpr int kF   = 64;
constexpr int kFE  = 16;
constexpr int kFil = 96;
constexpr int kDm  = 144;  // 2F + FE
constexpr int kDu  = 160;  // F + FILTERS
constexpr float kEps = 1e-3f;
constexpr int kBN = kB * kN;   // 40000
constexpr int kBE = kB * kE;   // 320000
constexpr int kHalf = kFil / 2;  // 48 outputs per thread (pair-split)
}

// ---------------------------------------------------------------------------
// CSR build: count -> scan -> scatter
// ---------------------------------------------------------------------------
__global__ void count_kernel(const int* __restrict__ edges, int* __restrict__ counts) {
    const int idx = blockIdx.x * 256 + threadIdx.x;
    if (idx >= kBE) return;
    const int b = idx / kE;
    const int dst = edges[(size_t)idx * 2 + 1];
    atomicAdd(&counts[b * kN + dst], 1);
}

__global__ __launch_bounds__(1024) void scan_kernel(const int* __restrict__ counts,
                                                    int* __restrict__ offsets) {
    __shared__ int part[1024];
    const int t = threadIdx.x;
    const int chunk = (kBN + 1023) / 1024;   // 40
    const int base = t * chunk;
    int s = 0;
    for (int i = 0; i < chunk; ++i) {
        const int j = base + i;
        if (j < kBN) s += counts[j];
    }
    part[t] = s;
    __syncthreads();
    for (int d = 1; d < 1024; d <<= 1) {
        const int v = (t >= d) ? part[t - d] : 0;
        __syncthreads();
        part[t] += v;
        __syncthreads();
    }
    int run = part[t] - s;   // exclusive prefix
    for (int i = 0; i < chunk; ++i) {
        const int j = base + i;
        if (j < kBN) {
            offsets[j] = run;
            run += counts[j];
        }
    }
}

__global__ void scatter_kernel(const int* __restrict__ edges,
                               const int* __restrict__ offsets,
                               int* __restrict__ cursor,
                               int* __restrict__ edge_ids) {
    const int idx = blockIdx.x * 256 + threadIdx.x;
    if (idx >= kBE) return;
    const int b = idx / kE;
    const int dst = edges[(size_t)idx * 2 + 1];
    const int node = b * kN + dst;
    const int pos = offsets[node] + atomicAdd(&cursor[node], 1);
    edge_ids[pos] = idx;
}

// ---------------------------------------------------------------------------
// Message: 2 threads per edge, each owns 48 of 96 outputs (acc[48] => no
// VGPR spill; round-2's acc[96] @ 64 VGPRs spilled ~350MB of scratch).
// LN stats pair-combined via shfl_xor(1). Each lane stores 192B = 3 full
// 64B lines.
// ---------------------------------------------------------------------------
__global__ __attribute__((amdgpu_flat_work_group_size(512, 512),
                          amdgpu_waves_per_eu(4, 4)))
void gnn_msg_kernel(
    const float* __restrict__ nodes,   // (B,N,F)
    const float* __restrict__ efeat,   // (B,E,FE)
    const int*   __restrict__ edges,   // (B,E,2)
    const float* __restrict__ Wm,      // (144,96)
    const float* __restrict__ bm,      // (96)
    const float* __restrict__ gamma_,  // (96)
    const float* __restrict__ beta_,   // (96)
    float* __restrict__ out_msg)       // (B,E,96)
{
    __shared__ float sW[kDm * kFil];          // 55296 B
    __shared__ float sb[kFil], sg[kFil], sbe[kFil];

    for (int i = threadIdx.x; i < kDm * kFil; i += 512) sW[i] = Wm[i];
    if (threadIdx.x < kFil) {
        sb[threadIdx.x]  = bm[threadIdx.x];
        sg[threadIdx.x]  = gamma_[threadIdx.x];
        sbe[threadIdx.x] = beta_[threadIdx.x];
    }
    __syncthreads();

    const int t    = blockIdx.x * 512 + threadIdx.x;  // 640000 threads exact
    const int edge = t >> 1;                          // flat b*E + e
    const int h    = t & 1;                           // half: 0 -> cols 0..47
    const int b    = edge / kE;

    const int src = edges[(size_t)edge * 2 + 0];
    const int dst = edges[(size_t)edge * 2 + 1];

    const float* srow = nodes + ((size_t)b * kN + src) * kF;
    const float* drow = nodes + ((size_t)b * kN + dst) * kF;
    const float* erow = efeat + (size_t)edge * kFE;

    float acc[kHalf];
    const int hc = h * kHalf;
#pragma unroll
    for (int f = 0; f < kHalf; ++f) acc[f] = sb[hc + f];

    // 9 chunks of 16 inputs: 0..3 -> src row, 4..7 -> dst row, 8 -> edge feats
#pragma unroll 1
    for (int kc = 0; kc < 9; ++kc) {
        const float* bptr;
        if (kc < 4)      bptr = srow + kc * 16;
        else if (kc < 8) bptr = drow + (kc - 4) * 16;
        else             bptr = erow;
        const float4* p4 = reinterpret_cast<const float4*>(bptr);
        float4 x0 = p4[0], x1 = p4[1], x2 = p4[2], x3 = p4[3];
        float xin[16] = {x0.x, x0.y, x0.z, x0.w, x1.x, x1.y, x1.z, x1.w,
                         x2.x, x2.y, x2.z, x2.w, x3.x, x3.y, x3.z, x3.w};
        const float* wbase = &sW[(size_t)kc * 16 * kFil + hc];
#pragma unroll
        for (int kk = 0; kk < 16; ++kk) {
            const float x = xin[kk];
            const float* wrow = wbase + kk * kFil;
#pragma unroll
            for (int f = 0; f < kHalf; ++f)
                acc[f] = fmaf(x, wrow[f], acc[f]);
        }
    }

    // ReLU + LayerNorm: stats over 96 = own 48 + partner 48 (shfl_xor lane^1)
    float s = 0.f;
#pragma unroll
    for (int f = 0; f < kHalf; ++f) {
        acc[f] = fmaxf(acc[f], 0.f);
        s += acc[f];
    }
    s += __shfl_xor(s, 1);
    const float mu = s * (1.0f / kFil);
    float v = 0.f;
#pragma unroll
    for (int f = 0; f < kHalf; ++f) {
        const float d = acc[f] - mu;
        v = fmaf(d, d, v);
    }
    v += __shfl_xor(v, 1);
    const float inv = rsqrtf(v * (1.0f / kFil) + kEps);
#pragma unroll
    for (int f = 0; f < kHalf; ++f)
        acc[f] = (acc[f] - mu) * inv * sg[hc + f] + sbe[hc + f];

    float* mrow = out_msg + (size_t)edge * kFil + hc;  // 192B, 64B-aligned
#pragma unroll
    for (int f = 0; f < kHalf; f += 4) {
        float4 o = {acc[f], acc[f + 1], acc[f + 2], acc[f + 3]};
        *reinterpret_cast<float4*>(mrow + f) = o;
    }
}

// ---------------------------------------------------------------------------
// Aggregate: one wave per node; lanes = 24 col-chunks x 2 edge-parity.
// Pair-combine via shfl_xor(32). Each message row read as coalesced 384B.
// ---------------------------------------------------------------------------
__global__ __launch_bounds__(256) void agg_kernel(
    const float* __restrict__ msg,        // (B,E,96)
    const int*   __restrict__ offsets,    // (B*N)
    const int*   __restrict__ counts,     // (B*N)
    const int*   __restrict__ edge_ids,   // (B*E)
    float* __restrict__ agg)              // (B,N,96)
{
    const int wave = threadIdx.x >> 6;
    const int lane = threadIdx.x & 63;
    const int node = blockIdx.x * 4 + wave;
    if (node >= kBN) return;
    const int start = offsets[node];
    const int cnt   = counts[node];
    const int p = lane >> 5;      // edge parity
    const int c = lane & 31;      // float4 column chunk (0..23 active)
    float4 acc = {0.f, 0.f, 0.f, 0.f};
    if (c < 24) {
        for (int e = p; e < cnt; e += 2) {
            const int eid = edge_ids[start + e];
            const float4 x =
                reinterpret_cast<const float4*>(msg + (size_t)eid * kFil)[c];
            acc.x += x.x; acc.y += x.y; acc.z += x.z; acc.w += x.w;
        }
    }
    acc.x += __shfl_xor(acc.x, 32);
    acc.y += __shfl_xor(acc.y, 32);
    acc.z += __shfl_xor(acc.z, 32);
    acc.w += __shfl_xor(acc.w, 32);
    if (p == 0 && c < 24)
        reinterpret_cast<float4*>(agg + (size_t)node * kFil)[c] = acc;
}

// ---------------------------------------------------------------------------
// Update: 2 threads per node, each owns 48 outputs.
// ---------------------------------------------------------------------------
__global__ __attribute__((amdgpu_flat_work_group_size(512, 512),
                          amdgpu_waves_per_eu(4, 4)))
void gnn_upd_kernel(
    const float* __restrict__ nodes,   // (B,N,F)
    const float* __restrict__ agg,     // (B,N,96)
    const float* __restrict__ Wu,      // (160,96)
    const float* __restrict__ bu,      // (96)
    const float* __restrict__ gamma_,  // (96)
    const float* __restrict__ beta_,   // (96)
    float* __restrict__ out_upd)       // (B,N,96)
{
    __shared__ float sW[kDu * kFil];          // 61440 B
    __shared__ float sb[kFil], sg[kFil], sbe[kFil];

    for (int i = threadIdx.x; i < kDu * kFil; i += 512) sW[i] = Wu[i];
    if (threadIdx.x < kFil) {
        sb[threadIdx.x]  = bu[threadIdx.x];
        sg[threadIdx.x]  = gamma_[threadIdx.x];
        sbe[threadIdx.x] = beta_[threadIdx.x];
    }
    __syncthreads();

    const int t    = blockIdx.x * 512 + threadIdx.x;
    const int idx  = t >> 1;            // flat b*N + n
    const int h    = t & 1;
    if (idx >= kBN) return;

    const float* srow = nodes + (size_t)idx * kF;
    const float* arow = agg + (size_t)idx * kFil;

    float acc[kHalf];
    const int hc = h * kHalf;
#pragma unroll
    for (int f = 0; f < kHalf; ++f) acc[f] = sb[hc + f];

#pragma unroll 1
    for (int kc = 0; kc < 10; ++kc) {
        const float* bptr;
        if (kc < 4) bptr = srow + kc * 16;
        else        bptr = arow + (kc - 4) * 16;
        const float4* p4 = reinterpret_cast<const float4*>(bptr);
        float4 x0 = p4[0], x1 = p4[1], x2 = p4[2], x3 = p4[3];
        float xin[16] = {x0.x, x0.y, x0.z, x0.w, x1.x, x1.y, x1.z, x1.w,
                         x2.x, x2.y, x2.z, x2.w, x3.x, x3.y, x3.z, x3.w};
        const float* wbase = &sW[(size_t)kc * 16 * kFil + hc];
#pragma unroll
        for (int kk = 0; kk < 16; ++kk) {
            const float x = xin[kk];
            const float* wrow = wbase + kk * kFil;
#pragma unroll
            for (int f = 0; f < kHalf; ++f)
                acc[f] = fmaf(x, wrow[f], acc[f]);
        }
    }

    float s = 0.f;
#pragma unroll
    for (int f = 0; f < kHalf; ++f) {
        acc[f] = fmaxf(acc[f], 0.f);
        s += acc[f];
    }
    s += __shfl_xor(s, 1);
    const float mu = s * (1.0f / kFil);
    float v = 0.f;
#pragma unroll
    for (int f = 0; f < kHalf; ++f) {
        const float d = acc[f] - mu;
        v = fmaf(d, d, v);
    }
    v += __shfl_xor(v, 1);
    const float inv = rsqrtf(v * (1.0f / kFil) + kEps);
#pragma unroll
    for (int f = 0; f < kHalf; ++f)
        acc[f] = (acc[f] - mu) * inv * sg[hc + f] + sbe[hc + f];

    float* orow = out_upd + (size_t)idx * kFil + hc;
#pragma unroll
    for (int f = 0; f < kHalf; f += 4) {
        float4 o = {acc[f], acc[f + 1], acc[f + 2], acc[f + 3]};
        *reinterpret_cast<float4*>(orow + f) = o;
    }
}

extern "C" void kernel_launch(void* const* d_in, const int* in_sizes, int n_in,
                              void* d_out, int out_size, void* d_ws, size_t ws_size,
                              hipStream_t stream) {
    const float* nodes  = (const float*)d_in[0];
    const float* efeat  = (const float*)d_in[1];
    const int*   edges  = (const int*)d_in[2];
    const float* Wm     = (const float*)d_in[3];
    const float* bm     = (const float*)d_in[4];
    const float* ln_m_g = (const float*)d_in[5];
    const float* ln_m_b = (const float*)d_in[6];
    const float* Wu     = (const float*)d_in[7];
    const float* bu     = (const float*)d_in[8];
    const float* ln_u_g = (const float*)d_in[9];
    const float* ln_u_b = (const float*)d_in[10];

    float* out_upd = (float*)d_out;                           // (B,N,96) first
    float* out_msg = (float*)d_out + (size_t)kBN * kFil;      // (B,E,96) second

    // workspace layout (~17.1 MB)
    float* agg      = (float*)d_ws;                           // B*N*96 floats
    int*   counts   = (int*)(agg + (size_t)kBN * kFil);       // 40000
    int*   cursor   = counts + kBN;                           // 40000
    int*   offsets  = cursor + kBN;                           // 40000
    int*   edge_ids = offsets + kBN;                          // 320000

    hipMemsetAsync(counts, 0, (size_t)2 * kBN * sizeof(int), stream);

    count_kernel<<<(kBE + 255) / 256, 256, 0, stream>>>(edges, counts);
    scan_kernel<<<1, 1024, 0, stream>>>(counts, offsets);
    scatter_kernel<<<(kBE + 255) / 256, 256, 0, stream>>>(edges, offsets, cursor, edge_ids);

    gnn_msg_kernel<<<kBE * 2 / 512, 512, 0, stream>>>(
        nodes, efeat, edges, Wm, bm, ln_m_g, ln_m_b, out_msg);
    agg_kernel<<<(kBN + 3) / 4, 256, 0, stream>>>(
        out_msg, offsets, counts, edge_ids, agg);
    gnn_upd_kernel<<<(kBN * 2 + 511) / 512, 512, 0, stream>>>(
        nodes, agg, Wu, bu, ln_u_g, ln_u_b, out_upd);
}